// Round 1
// baseline (392.128 us; speedup 1.0000x reference)
//
#include <hip/hip_runtime.h>
#include <cstdint>
#include <cstddef>

#define Bn 8
#define Nn 2048
#define Fn 64
#define ALPHA 0.2f
#define CAP 192   // padded CSR row capacity; mean nnz/row = 102.4, sd 9.9 -> 9 sigma headroom

__device__ __forceinline__ float lrelu(float x) { return fmaxf(x, ALPHA * x); }
__device__ __forceinline__ float elu(float x)   { return x > 0.f ? x : __expf(x) - 1.f; }

// ---------------- k1: h = input@W, f1 = h@a1, f2 = h@a2 ----------------
__global__ __launch_bounds__(256) void k1_h_f(
        const float* __restrict__ inp, const float* __restrict__ W,
        const float* __restrict__ a1, const float* __restrict__ a2,
        float* __restrict__ h, float* __restrict__ f1, float* __restrict__ f2) {
    __shared__ float Wl[Fn * Fn];
    __shared__ float inr[4 * Fn];
    int t = threadIdx.x;
    for (int k = t; k < Fn * Fn; k += 256) Wl[k] = W[k];
    size_t row0 = (size_t)blockIdx.x * 4;
    inr[t] = inp[row0 * Fn + t];
    __syncthreads();
    int r = t >> 6, o = t & 63;
    const float* irow = &inr[r * Fn];
    float acc = 0.f;
#pragma unroll
    for (int f = 0; f < Fn; ++f) acc = fmaf(irow[f], Wl[f * Fn + o], acc);
    size_t row = row0 + r;
    h[row * Fn + o] = acc;
    float p = acc * a1[o];
    float q = acc * a2[o];
#pragma unroll
    for (int off = 32; off > 0; off >>= 1) {
        p += __shfl_down(p, off, 64);
        q += __shfl_down(q, off, 64);
    }
    if (o == 0) { f1[row] = p; f2[row] = q; }
}

// ---------------- k1b: f1max[b] = max_i f1[b,i] ----------------
__global__ __launch_bounds__(256) void k1b_max(
        const float* __restrict__ f1, float* __restrict__ f1max) {
    int b = blockIdx.x, t = threadIdx.x;
    float m = -3.4e38f;
    for (int i = t; i < Nn; i += 256) m = fmaxf(m, f1[b * Nn + i]);
#pragma unroll
    for (int off = 32; off > 0; off >>= 1) m = fmaxf(m, __shfl_down(m, off, 64));
    __shared__ float sm[4];
    if ((t & 63) == 0) sm[t >> 6] = m;
    __syncthreads();
    if (t == 0) f1max[b] = fmaxf(fmaxf(sm[0], sm[1]), fmaxf(sm[2], sm[3]));
}

// ------- k2a: stream adj once -> padded CSR (u16 col idx) + column sums Dsum (rank-1, exp-free) -------
// grid (Bn, 8 colchunks of 256, 16 rowchunks of 128), block 512.
__global__ __launch_bounds__(512) void k2a_csr(
        const float* __restrict__ adj, const float* __restrict__ f1,
        const float* __restrict__ f2, const float* __restrict__ f1max_p,
        float* __restrict__ Dsum, unsigned* __restrict__ rowcnt,
        unsigned short* __restrict__ csr) {
    int b = blockIdx.x;
    int j0 = blockIdx.y * 256;
    int i0 = blockIdx.z * 128;
    int w = threadIdx.x >> 6, lane = threadIdx.x & 63;
    float f1max = f1max_p[b];
    float4 f2v = *(const float4*)&f2[b * Nn + j0 + 4 * lane];
    float Mf0 = fmaxf(lrelu(f1max + f2v.x), 0.f);
    float Mf1 = fmaxf(lrelu(f1max + f2v.y), 0.f);
    float Mf2 = fmaxf(lrelu(f1max + f2v.z), 0.f);
    float Mf3 = fmaxf(lrelu(f1max + f2v.w), 0.f);
    float vh0 = __expf(f2v.x - Mf0), vp0 = __expf(ALPHA * f2v.x - Mf0), ez0 = __expf(-Mf0);
    float vh1 = __expf(f2v.y - Mf1), vp1 = __expf(ALPHA * f2v.y - Mf1), ez1 = __expf(-Mf1);
    float vh2 = __expf(f2v.z - Mf2), vp2 = __expf(ALPHA * f2v.z - Mf2), ez2 = __expf(-Mf2);
    float vh3 = __expf(f2v.w - Mf3), vp3 = __expf(ALPHA * f2v.w - Mf3), ez3 = __expf(-Mf3);
    float s0 = 0.f, s1 = 0.f, s2 = 0.f, s3 = 0.f;
    const float* abase = adj + ((size_t)b * Nn) * Nn + j0 + 4 * lane;
    const float* f1b = f1 + b * Nn;

    int rb = i0 + w;
    float4 av0 = *(const float4*)(abase + (size_t)(rb +  0) * Nn);
    float4 av1 = *(const float4*)(abase + (size_t)(rb +  8) * Nn);
    float4 av2 = *(const float4*)(abase + (size_t)(rb + 16) * Nn);
    float4 av3 = *(const float4*)(abase + (size_t)(rb + 24) * Nn);
    float fi0 = f1b[rb], fi1 = f1b[rb + 8], fi2 = f1b[rb + 16], fi3 = f1b[rb + 24];

// ballot-compacted CSR append: 1 atomic per wave per column, consecutive slots
#define APPEND(NK, RROW, COL)                                                  \
        {                                                                      \
            unsigned long long mk = __ballot(NK);                              \
            if (mk) {                                                          \
                unsigned basek = 0;                                            \
                if (lane == 0)                                                 \
                    basek = atomicAdd(&rowcnt[RROW], (unsigned)__popcll(mk));  \
                basek = (unsigned)__shfl((int)basek, 0, 64);                   \
                if (NK) {                                                      \
                    unsigned sl = basek +                                      \
                        (unsigned)__popcll(mk & ((1ull << lane) - 1ull));      \
                    if (sl < CAP)                                              \
                        csr[(size_t)(RROW) * CAP + sl] = (unsigned short)(COL);\
                }                                                              \
            }                                                                  \
        }

    for (int gi = 0; gi < 4; ++gi) {
        int rc = i0 + w + 32 * gi;
        float4 nv0, nv1, nv2, nv3;
        float nf0 = 0.f, nf1 = 0.f, nf2 = 0.f, nf3 = 0.f;
        if (gi < 3) {
            int rn = rc + 32;
            nv0 = *(const float4*)(abase + (size_t)(rn +  0) * Nn);
            nv1 = *(const float4*)(abase + (size_t)(rn +  8) * Nn);
            nv2 = *(const float4*)(abase + (size_t)(rn + 16) * Nn);
            nv3 = *(const float4*)(abase + (size_t)(rn + 24) * Nn);
            nf0 = f1b[rn]; nf1 = f1b[rn + 8]; nf2 = f1b[rn + 16]; nf3 = f1b[rn + 24];
        }
#define PROC(AV, FI, IROW)                                                     \
        {                                                                      \
            float u  = __expf(FI);                                             \
            float up = __expf(ALPHA * (FI));                                   \
            bool n0 = AV.x != 0.f, n1 = AV.y != 0.f,                           \
                 n2 = AV.z != 0.f, n3 = AV.w != 0.f;                           \
            float x0 = (FI) + f2v.x, x1 = (FI) + f2v.y,                        \
                  x2 = (FI) + f2v.z, x3 = (FI) + f2v.w;                        \
            float e0 = x0 > 0.f ? u * vh0 : up * vp0;                          \
            float e1 = x1 > 0.f ? u * vh1 : up * vp1;                          \
            float e2 = x2 > 0.f ? u * vh2 : up * vp2;                          \
            float e3 = x3 > 0.f ? u * vh3 : up * vp3;                          \
            s0 += n0 ? e0 : ez0;                                               \
            s1 += n1 ? e1 : ez1;                                               \
            s2 += n2 ? e2 : ez2;                                               \
            s3 += n3 ? e3 : ez3;                                               \
            unsigned rrow = (unsigned)(b * Nn + (IROW));                       \
            APPEND(n0, rrow, j0 + 4 * lane + 0)                                \
            APPEND(n1, rrow, j0 + 4 * lane + 1)                                \
            APPEND(n2, rrow, j0 + 4 * lane + 2)                                \
            APPEND(n3, rrow, j0 + 4 * lane + 3)                                \
        }
        PROC(av0, fi0, rc +  0)
        PROC(av1, fi1, rc +  8)
        PROC(av2, fi2, rc + 16)
        PROC(av3, fi3, rc + 24)
#undef PROC
#undef APPEND
        av0 = nv0; av1 = nv1; av2 = nv2; av3 = nv3;
        fi0 = nf0; fi1 = nf1; fi2 = nf2; fi3 = nf3;
    }
    __shared__ float sred[8][256];
    sred[w][4 * lane + 0] = s0;
    sred[w][4 * lane + 1] = s1;
    sred[w][4 * lane + 2] = s2;
    sred[w][4 * lane + 3] = s3;
    __syncthreads();
    if (threadIdx.x < 256) {
        int c = threadIdx.x;
        float v = 0.f;
#pragma unroll
        for (int k = 0; k < 8; ++k) v += sred[k][c];
        atomicAdd(&Dsum[b * Nn + j0 + c], v);
    }
}

// ------- k2b: per-column table cf4 = {f2, vh/D, vp/D, ez/D}  +  rank-1 base C[b][o] = sum_j (ez_j/D_j) h[j][o] -------
// grid (Bn, Nn/64), block 256
__global__ __launch_bounds__(256) void k2b_cols(
        const float* __restrict__ h, const float* __restrict__ Dsum,
        const float* __restrict__ f2, const float* __restrict__ f1max_p,
        float4* __restrict__ cf4, float* __restrict__ C) {
    int b = blockIdx.x;
    int j0 = blockIdx.y * 64;
    int t = threadIdx.x;
    __shared__ float zl[64];
    if (t < 64) {
        int j = j0 + t;
        float f2j = f2[b * Nn + j];
        float Mf = fmaxf(lrelu(f1max_p[b] + f2j), 0.f);
        float invD = 1.f / Dsum[b * Nn + j];
        float vh = __expf(f2j - Mf) * invD;
        float vp = __expf(ALPHA * f2j - Mf) * invD;
        float ez = __expf(-Mf) * invD;
        cf4[b * Nn + j] = make_float4(f2j, vh, vp, ez);
        zl[t] = ez;
    }
    __syncthreads();
    int o = t & 63, g = t >> 6;      // 4 groups x 16 columns
    const float* hbp = h + ((size_t)(b * Nn + j0 + g * 16)) * Fn + o;
    float s = 0.f;
#pragma unroll
    for (int k = 0; k < 16; ++k) s = fmaf(zl[g * 16 + k], hbp[(size_t)k * Fn], s);
    atomicAdd(&C[b * Fn + o], s);
}

// ------- k3: sparse gather-accumulate. wave = one output row i, lane = feature o -------
// h'[i,:] = C_b + sum_{nnz j} ((uv_ij - ez_j)/D_j) * h[j,:]; epilogue adds inp+bias, elu.
// grid (Bn, Nn/4), block 256 (4 waves)
__global__ __launch_bounds__(256) void k3_sparse(
        const unsigned short* __restrict__ csr, const unsigned* __restrict__ rowcnt,
        const float4* __restrict__ cf4, const float* __restrict__ f1,
        const float* __restrict__ h, const float* __restrict__ C,
        const float* __restrict__ inp, const float* __restrict__ bias,
        float* __restrict__ out) {
    int b = blockIdx.x;
    int w = threadIdx.x >> 6, lane = threadIdx.x & 63;
    int i = blockIdx.y * 4 + w;
    size_t rb = (size_t)b * Nn + i;
    unsigned cnt = rowcnt[rb];
    if (cnt > CAP) cnt = CAP;
    float f1i = f1[rb];
    float ui = __expf(f1i), upi = __expf(ALPHA * f1i);
    const unsigned short* lst = csr + rb * CAP;
    const float4* cfb = cf4 + (size_t)b * Nn;
    const float* hb = h + ((size_t)b * Nn) * Fn + lane;
    float acc = C[b * Fn + lane];

    for (unsigned c0 = 0; c0 < cnt; c0 += 64) {
        int m = (int)(cnt - c0 < 64u ? cnt - c0 : 64u);
        int idx = (lane < m) ? (int)lst[c0 + lane] : 0;   // coalesced 128B u16 load
        int jc = __shfl(idx, 0, 64);
        float4 cfa = cfb[jc];                  // broadcast 16B load (L2 hit)
        float hva = hb[(size_t)jc * Fn];       // coalesced 256B row load (L2 resident)
        for (int t = 0; t < m; ++t) {
            float4 cf = cfa;
            float hv = hva;
            if (t + 1 < m) {                   // depth-1 prefetch of next neighbor
                int jn = __shfl(idx, t + 1, 64);
                cfa = cfb[jn];
                hva = hb[(size_t)jn * Fn];
            }
            float x = f1i + cf.x;
            float wv = (x > 0.f ? ui * cf.y : upi * cf.z) - cf.w;
            acc = fmaf(wv, hv, acc);
        }
    }
    size_t gbase = rb * Fn + lane;
    float r = acc + inp[gbase] + bias[(size_t)i * Fn + lane];
    out[gbase] = elu(r);
}

extern "C" void kernel_launch(void* const* d_in, const int* in_sizes, int n_in,
                              void* d_out, int out_size, void* d_ws, size_t ws_size,
                              hipStream_t stream) {
    const float* inp  = (const float*)d_in[0];
    const float* adj  = (const float*)d_in[1];
    const float* W    = (const float*)d_in[2];
    const float* a1   = (const float*)d_in[3];
    const float* a2   = (const float*)d_in[4];
    const float* bias = (const float*)d_in[5];
    float* out = (float*)d_out;

    // workspace layout (~10.5 MiB)
    char* ws = (char*)d_ws;
    unsigned short* csr = (unsigned short*)ws;                 // 8*2048*192*2 = 6,291,456
    float*  h     = (float*)(ws + 6291456);                    // 8*2048*64*4  = 4,194,304
    float4* cf4   = (float4*)(ws + 10485760);                  // 16K*16       =   262,144
    float*  f1    = (float*)(ws + 10747904);                   //                  65,536
    float*  f2    = (float*)(ws + 10813440);                   //                  65,536
    float*  f1max = (float*)(ws + 10878976);                   //                      32 (+pad)
    float*  Dsum  = (float*)(ws + 10879040);                   //                  65,536 (zeroed)
    unsigned* rowcnt = (unsigned*)(ws + 10944576);             //                  65,536 (zeroed)
    float*  C     = (float*)(ws + 11010112);                   //                   2,048 (zeroed)

    hipMemsetAsync(ws + 10879040, 0, 65536 + 65536 + 2048, stream);
    k1_h_f<<<Bn * Nn / 4, 256, 0, stream>>>(inp, W, a1, a2, h, f1, f2);
    k1b_max<<<Bn, 256, 0, stream>>>(f1, f1max);
    k2a_csr<<<dim3(Bn, 8, 16), 512, 0, stream>>>(adj, f1, f2, f1max, Dsum, rowcnt, csr);
    k2b_cols<<<dim3(Bn, Nn / 64), 256, 0, stream>>>(h, Dsum, f2, f1max, cf4, C);
    k3_sparse<<<dim3(Bn, Nn / 4), 256, 0, stream>>>(csr, rowcnt, cf4, f1, h, C, inp, bias, out);
}

// Round 2
// 312.802 us; speedup vs baseline: 1.2536x; 1.2536x over previous
//
#include <hip/hip_runtime.h>
#include <cstdint>
#include <cstddef>

#define Bn 8
#define Nn 2048
#define Fn 64
#define ALPHA 0.2f

__device__ __forceinline__ float lrelu(float x) { return fmaxf(x, ALPHA * x); }
__device__ __forceinline__ float elu(float x)   { return x > 0.f ? x : __expf(x) - 1.f; }

// ---------------- k1: h = input@W, f1 = h@a1, f2 = h@a2 ----------------
__global__ __launch_bounds__(256) void k1_h_f(
        const float* __restrict__ inp, const float* __restrict__ W,
        const float* __restrict__ a1, const float* __restrict__ a2,
        float* __restrict__ h, float* __restrict__ f1, float* __restrict__ f2) {
    __shared__ float Wl[Fn * Fn];
    __shared__ float inr[4 * Fn];
    int t = threadIdx.x;
    for (int k = t; k < Fn * Fn; k += 256) Wl[k] = W[k];
    size_t row0 = (size_t)blockIdx.x * 4;
    inr[t] = inp[row0 * Fn + t];
    __syncthreads();
    int r = t >> 6, o = t & 63;
    const float* irow = &inr[r * Fn];
    float acc = 0.f;
#pragma unroll
    for (int f = 0; f < Fn; ++f) acc = fmaf(irow[f], Wl[f * Fn + o], acc);
    size_t row = row0 + r;
    h[row * Fn + o] = acc;
    float p = acc * a1[o];
    float q = acc * a2[o];
#pragma unroll
    for (int off = 32; off > 0; off >>= 1) {
        p += __shfl_down(p, off, 64);
        q += __shfl_down(q, off, 64);
    }
    if (o == 0) { f1[row] = p; f2[row] = q; }
}

// ---------------- k1b: f1max[b] = max_i f1[b,i] ----------------
__global__ __launch_bounds__(256) void k1b_max(
        const float* __restrict__ f1, float* __restrict__ f1max) {
    int b = blockIdx.x, t = threadIdx.x;
    float m = -3.4e38f;
    for (int i = t; i < Nn; i += 256) m = fmaxf(m, f1[b * Nn + i]);
#pragma unroll
    for (int off = 32; off > 0; off >>= 1) m = fmaxf(m, __shfl_down(m, off, 64));
    __shared__ float sm[4];
    if ((t & 63) == 0) sm[t >> 6] = m;
    __syncthreads();
    if (t == 0) f1max[b] = fmaxf(fmaxf(sm[0], sm[1]), fmaxf(sm[2], sm[3]));
}

// ------- k2a: stream adj once -> row-major bit words + column sums Dsum (rank-1, exp-free) -------
// grid (Bn, 8 colchunks of 256, 16 rowchunks of 128), block 512.
// bitsW[row*64 + wd] bit k = adj[row][32*wd + k] != 0. No atomics (except Dsum reduce).
__global__ __launch_bounds__(512) void k2a_bits(
        const float* __restrict__ adj, const float* __restrict__ f1,
        const float* __restrict__ f2, const float* __restrict__ f1max_p,
        float* __restrict__ Dsum, unsigned* __restrict__ bitsW) {
    int b = blockIdx.x;
    int j0 = blockIdx.y * 256;
    int cj8 = blockIdx.y * 8;
    int i0 = blockIdx.z * 128;
    int w = threadIdx.x >> 6, lane = threadIdx.x & 63;
    float f1max = f1max_p[b];
    float4 f2v = *(const float4*)&f2[b * Nn + j0 + 4 * lane];
    float Mf0 = fmaxf(lrelu(f1max + f2v.x), 0.f);
    float Mf1 = fmaxf(lrelu(f1max + f2v.y), 0.f);
    float Mf2 = fmaxf(lrelu(f1max + f2v.z), 0.f);
    float Mf3 = fmaxf(lrelu(f1max + f2v.w), 0.f);
    float vh0 = __expf(f2v.x - Mf0), vp0 = __expf(ALPHA * f2v.x - Mf0), ez0 = __expf(-Mf0);
    float vh1 = __expf(f2v.y - Mf1), vp1 = __expf(ALPHA * f2v.y - Mf1), ez1 = __expf(-Mf1);
    float vh2 = __expf(f2v.z - Mf2), vp2 = __expf(ALPHA * f2v.z - Mf2), ez2 = __expf(-Mf2);
    float vh3 = __expf(f2v.w - Mf3), vp3 = __expf(ALPHA * f2v.w - Mf3), ez3 = __expf(-Mf3);
    float s0 = 0.f, s1 = 0.f, s2 = 0.f, s3 = 0.f;
    const float* abase = adj + ((size_t)b * Nn) * Nn + j0 + 4 * lane;
    const float* f1b = f1 + b * Nn;

    int rb = i0 + w;
    float4 av0 = *(const float4*)(abase + (size_t)(rb +  0) * Nn);
    float4 av1 = *(const float4*)(abase + (size_t)(rb +  8) * Nn);
    float4 av2 = *(const float4*)(abase + (size_t)(rb + 16) * Nn);
    float4 av3 = *(const float4*)(abase + (size_t)(rb + 24) * Nn);
    float fi0 = f1b[rb], fi1 = f1b[rb + 8], fi2 = f1b[rb + 16], fi3 = f1b[rb + 24];

    for (int gi = 0; gi < 4; ++gi) {
        int rc = i0 + w + 32 * gi;
        float4 nv0, nv1, nv2, nv3;
        float nf0 = 0.f, nf1 = 0.f, nf2 = 0.f, nf3 = 0.f;
        if (gi < 3) {
            int rn = rc + 32;
            nv0 = *(const float4*)(abase + (size_t)(rn +  0) * Nn);
            nv1 = *(const float4*)(abase + (size_t)(rn +  8) * Nn);
            nv2 = *(const float4*)(abase + (size_t)(rn + 16) * Nn);
            nv3 = *(const float4*)(abase + (size_t)(rn + 24) * Nn);
            nf0 = f1b[rn]; nf1 = f1b[rn + 8]; nf2 = f1b[rn + 16]; nf3 = f1b[rn + 24];
        }
        // register-packed bit build: nib(4 cols) -> byte -> u16 -> u32, one store per 32 cols
#define PROC(AV, FI, IROW)                                                     \
        {                                                                      \
            float u  = __expf(FI);                                             \
            float up = __expf(ALPHA * (FI));                                   \
            bool n0 = AV.x != 0.f, n1 = AV.y != 0.f,                           \
                 n2 = AV.z != 0.f, n3 = AV.w != 0.f;                           \
            float x0 = (FI) + f2v.x, x1 = (FI) + f2v.y,                        \
                  x2 = (FI) + f2v.z, x3 = (FI) + f2v.w;                        \
            float e0 = x0 > 0.f ? u * vh0 : up * vp0;                          \
            float e1 = x1 > 0.f ? u * vh1 : up * vp1;                          \
            float e2 = x2 > 0.f ? u * vh2 : up * vp2;                          \
            float e3 = x3 > 0.f ? u * vh3 : up * vp3;                          \
            s0 += n0 ? e0 : ez0;                                               \
            s1 += n1 ? e1 : ez1;                                               \
            s2 += n2 ? e2 : ez2;                                               \
            s3 += n3 ? e3 : ez3;                                               \
            unsigned nib = (unsigned)n0 | ((unsigned)n1 << 1) |                \
                           ((unsigned)n2 << 2) | ((unsigned)n3 << 3);          \
            unsigned byt = nib | (((unsigned)__shfl_xor((int)nib, 1, 64)) << 4);\
            unsigned h16 = byt | (((unsigned)__shfl_xor((int)byt, 2, 64)) << 8);\
            unsigned w32 = h16 | (((unsigned)__shfl_xor((int)h16, 4, 64)) << 16);\
            if ((lane & 7) == 0)                                               \
                bitsW[(size_t)(b * Nn + (IROW)) * 64 + cj8 + (lane >> 3)] = w32;\
        }
        PROC(av0, fi0, rc +  0)
        PROC(av1, fi1, rc +  8)
        PROC(av2, fi2, rc + 16)
        PROC(av3, fi3, rc + 24)
#undef PROC
        av0 = nv0; av1 = nv1; av2 = nv2; av3 = nv3;
        fi0 = nf0; fi1 = nf1; fi2 = nf2; fi3 = nf3;
    }
    __shared__ float sred[8][256];
    sred[w][4 * lane + 0] = s0;
    sred[w][4 * lane + 1] = s1;
    sred[w][4 * lane + 2] = s2;
    sred[w][4 * lane + 3] = s3;
    __syncthreads();
    if (threadIdx.x < 256) {
        int c = threadIdx.x;
        float v = 0.f;
#pragma unroll
        for (int k = 0; k < 8; ++k) v += sred[k][c];
        atomicAdd(&Dsum[b * Nn + j0 + c], v);
    }
}

// ------- k2b: per-column table cf4 = {f2, vh/D, vp/D, ez/D}  +  rank-1 base C[b][o] = sum_j (ez_j/D_j) h[j][o] -------
// grid (Bn, Nn/64), block 256
__global__ __launch_bounds__(256) void k2b_cols(
        const float* __restrict__ h, const float* __restrict__ Dsum,
        const float* __restrict__ f2, const float* __restrict__ f1max_p,
        float4* __restrict__ cf4, float* __restrict__ C) {
    int b = blockIdx.x;
    int j0 = blockIdx.y * 64;
    int t = threadIdx.x;
    __shared__ float zl[64];
    if (t < 64) {
        int j = j0 + t;
        float f2j = f2[b * Nn + j];
        float Mf = fmaxf(lrelu(f1max_p[b] + f2j), 0.f);
        float invD = 1.f / Dsum[b * Nn + j];
        float vh = __expf(f2j - Mf) * invD;
        float vp = __expf(ALPHA * f2j - Mf) * invD;
        float ez = __expf(-Mf) * invD;
        cf4[b * Nn + j] = make_float4(f2j, vh, vp, ez);
        zl[t] = ez;
    }
    __syncthreads();
    int o = t & 63, g = t >> 6;      // 4 groups x 16 columns
    const float* hbp = h + ((size_t)(b * Nn + j0 + g * 16)) * Fn + o;
    float s = 0.f;
#pragma unroll
    for (int k = 0; k < 16; ++k) s = fmaf(zl[g * 16 + k], hbp[(size_t)k * Fn], s);
    atomicAdd(&C[b * Fn + o], s);
}

// ------- k3: block = one output row i; wave w decodes+gathers its quarter (512 cols) of the row -------
// h'[i,:] = C_b + sum_{nnz j} ((uv_ij - ez_j)/D_j) * h[j,:]; epilogue adds inp+bias, elu.
// grid (Bn*Nn), block 256 (4 waves)
__global__ __launch_bounds__(256) void k3_bits(
        const unsigned* __restrict__ bits, const float4* __restrict__ cf4,
        const float* __restrict__ f1, const float* __restrict__ h,
        const float* __restrict__ C, const float* __restrict__ inp,
        const float* __restrict__ bias, float* __restrict__ out) {
    int bid = blockIdx.x;
    int b = bid >> 11, i = bid & (Nn - 1);
    int w = threadIdx.x >> 6, lane = threadIdx.x & 63;
    size_t rb = (size_t)b * Nn + i;
    __shared__ unsigned short lst[4][128];
    __shared__ float red[4][Fn];
    __shared__ unsigned cnts[4];
    // phase 1: decode 16 words (512 cols) per wave into LDS index list
    if (lane < 16) {
        unsigned word = bits[rb * 64 + w * 16 + lane];
        unsigned pc = (unsigned)__popc(word);
        unsigned pre = pc;
#pragma unroll
        for (int off = 1; off < 16; off <<= 1) {
            unsigned v = (unsigned)__shfl_up((int)pre, off, 64);
            if (lane >= off) pre += v;
        }
        unsigned base = pre - pc;
        int jb = (w * 16 + lane) * 32;
        while (word) {
            int k = __ffs(word) - 1;
            word &= word - 1;
            lst[w][base++] = (unsigned short)(jb + k);
        }
        if (lane == 15) cnts[w] = pre;
    }
    float f1i = f1[rb];
    float ui = __expf(f1i), upi = __expf(ALPHA * f1i);
    __syncthreads();
    unsigned cnt = cnts[w];
    const float4* cfb = cf4 + (size_t)b * Nn;
    const float* hb = h + ((size_t)b * Nn) * Fn + lane;
    float acc = 0.f;
    // phase 2: gather with depth-2 software pipeline
    float4 c0 = {0,0,0,0}, c1 = {0,0,0,0};
    float h0 = 0.f, h1 = 0.f;
    if (cnt > 0) { int j = lst[w][0]; c0 = cfb[j]; h0 = hb[(size_t)j * Fn]; }
    if (cnt > 1) { int j = lst[w][1]; c1 = cfb[j]; h1 = hb[(size_t)j * Fn]; }
    for (unsigned t = 0; t < cnt; ++t) {
        float4 cc = c0; float hh = h0;
        c0 = c1; h0 = h1;
        if (t + 2 < cnt) {
            int j = lst[w][t + 2];
            c1 = cfb[j]; h1 = hb[(size_t)j * Fn];
        }
        float x = f1i + cc.x;
        float wv = (x > 0.f ? ui * cc.y : upi * cc.z) - cc.w;
        acc = fmaf(wv, hh, acc);
    }
    red[w][lane] = acc;
    __syncthreads();
    if (threadIdx.x < Fn) {
        int o = threadIdx.x;
        float v = red[0][o] + red[1][o] + red[2][o] + red[3][o] + C[b * Fn + o];
        size_t g = rb * Fn + o;
        out[g] = elu(v + inp[g] + bias[(size_t)i * Fn + o]);
    }
}

extern "C" void kernel_launch(void* const* d_in, const int* in_sizes, int n_in,
                              void* d_out, int out_size, void* d_ws, size_t ws_size,
                              hipStream_t stream) {
    const float* inp  = (const float*)d_in[0];
    const float* adj  = (const float*)d_in[1];
    const float* W    = (const float*)d_in[2];
    const float* a1   = (const float*)d_in[3];
    const float* a2   = (const float*)d_in[4];
    const float* bias = (const float*)d_in[5];
    float* out = (float*)d_out;

    // workspace layout (~8.5 MiB)
    char* ws = (char*)d_ws;
    unsigned* bitsW = (unsigned*)ws;                           // 8*2048*64*4 = 4,194,304
    float*  h     = (float*)(ws + 4194304);                    // 4,194,304
    float4* cf4   = (float4*)(ws + 8388608);                   //   262,144
    float*  f1    = (float*)(ws + 8650752);                    //    65,536
    float*  f2    = (float*)(ws + 8716288);                    //    65,536
    float*  f1max = (float*)(ws + 8781824);                    //        64 (pad)
    float*  Dsum  = (float*)(ws + 8781888);                    //    65,536 (zeroed)
    float*  C     = (float*)(ws + 8847424);                    //     2,048 (zeroed)

    hipMemsetAsync(ws + 8781888, 0, 65536 + 2048, stream);
    k1_h_f<<<Bn * Nn / 4, 256, 0, stream>>>(inp, W, a1, a2, h, f1, f2);
    k1b_max<<<Bn, 256, 0, stream>>>(f1, f1max);
    k2a_bits<<<dim3(Bn, 8, 16), 512, 0, stream>>>(adj, f1, f2, f1max, Dsum, bitsW);
    k2b_cols<<<dim3(Bn, Nn / 64), 256, 0, stream>>>(h, Dsum, f2, f1max, cf4, C);
    k3_bits<<<Bn * Nn, 256, 0, stream>>>(bitsW, cf4, f1, h, C, inp, bias, out);
}

// Round 3
// 262.507 us; speedup vs baseline: 1.4938x; 1.1916x over previous
//
#include <hip/hip_runtime.h>
#include <cstdint>
#include <cstddef>

#define Bn 8
#define Nn 2048
#define Fn 64
#define ALPHA 0.2f
#define CAPR 192   // per-row neighbor capacity; mean 102.4, sd 9.9 -> 9 sigma

__device__ __forceinline__ float lrelu(float x) { return fmaxf(x, ALPHA * x); }
__device__ __forceinline__ float elu(float x)   { return x > 0.f ? x : __expf(x) - 1.f; }

// ---------------- k1: h = input@W, f1 = h@a1, f2 = h@a2 ----------------
__global__ __launch_bounds__(256) void k1_h_f(
        const float* __restrict__ inp, const float* __restrict__ W,
        const float* __restrict__ a1, const float* __restrict__ a2,
        float* __restrict__ h, float* __restrict__ f1, float* __restrict__ f2) {
    __shared__ float Wl[Fn * Fn];
    __shared__ float inr[4 * Fn];
    int t = threadIdx.x;
    for (int k = t; k < Fn * Fn; k += 256) Wl[k] = W[k];
    size_t row0 = (size_t)blockIdx.x * 4;
    inr[t] = inp[row0 * Fn + t];
    __syncthreads();
    int r = t >> 6, o = t & 63;
    const float* irow = &inr[r * Fn];
    float acc = 0.f;
#pragma unroll
    for (int f = 0; f < Fn; ++f) acc = fmaf(irow[f], Wl[f * Fn + o], acc);
    size_t row = row0 + r;
    h[row * Fn + o] = acc;
    float p = acc * a1[o];
    float q = acc * a2[o];
#pragma unroll
    for (int off = 32; off > 0; off >>= 1) {
        p += __shfl_down(p, off, 64);
        q += __shfl_down(q, off, 64);
    }
    if (o == 0) { f1[row] = p; f2[row] = q; }
}

// ---------------- k1b: f1max[b] = max_i f1[b,i] ----------------
__global__ __launch_bounds__(256) void k1b_max(
        const float* __restrict__ f1, float* __restrict__ f1max) {
    int b = blockIdx.x, t = threadIdx.x;
    float m = -3.4e38f;
    for (int i = t; i < Nn; i += 256) m = fmaxf(m, f1[b * Nn + i]);
#pragma unroll
    for (int off = 32; off > 0; off >>= 1) m = fmaxf(m, __shfl_down(m, off, 64));
    __shared__ float sm[4];
    if ((t & 63) == 0) sm[t >> 6] = m;
    __syncthreads();
    if (t == 0) f1max[b] = fmaxf(fmaxf(sm[0], sm[1]), fmaxf(sm[2], sm[3]));
}

// ------- k2a: stream adj once -> row-major bit words + column sums Dsum (rank-1, exp-free) -------
// grid (Bn, 8 colchunks of 256, 32 rowchunks of 64), block 512.
// Thread (w,lane) handles rows i0+w+8q (q<8), cols j0+4*lane..+3. 8 dwordx4 in flight upfront.
__global__ __launch_bounds__(512) void k2a_bits(
        const float* __restrict__ adj, const float* __restrict__ f1,
        const float* __restrict__ f2, const float* __restrict__ f1max_p,
        float* __restrict__ Dsum, unsigned* __restrict__ bitsW) {
    int b = blockIdx.x;
    int j0 = blockIdx.y * 256;
    int cj8 = blockIdx.y * 8;
    int i0 = blockIdx.z * 64;
    int w = threadIdx.x >> 6, lane = threadIdx.x & 63;
    float f1max = f1max_p[b];
    float4 f2v = *(const float4*)&f2[b * Nn + j0 + 4 * lane];
    float Mf0 = fmaxf(lrelu(f1max + f2v.x), 0.f);
    float Mf1 = fmaxf(lrelu(f1max + f2v.y), 0.f);
    float Mf2 = fmaxf(lrelu(f1max + f2v.z), 0.f);
    float Mf3 = fmaxf(lrelu(f1max + f2v.w), 0.f);
    float vh0 = __expf(f2v.x - Mf0), vp0 = __expf(ALPHA * f2v.x - Mf0), ez0 = __expf(-Mf0);
    float vh1 = __expf(f2v.y - Mf1), vp1 = __expf(ALPHA * f2v.y - Mf1), ez1 = __expf(-Mf1);
    float vh2 = __expf(f2v.z - Mf2), vp2 = __expf(ALPHA * f2v.z - Mf2), ez2 = __expf(-Mf2);
    float vh3 = __expf(f2v.w - Mf3), vp3 = __expf(ALPHA * f2v.w - Mf3), ez3 = __expf(-Mf3);
    float s0 = 0.f, s1 = 0.f, s2 = 0.f, s3 = 0.f;
    const float* abase = adj + ((size_t)b * Nn) * Nn + j0 + 4 * lane;
    const float* f1b = f1 + b * Nn;

    float4 av[8]; float fi[8];
#pragma unroll
    for (int q = 0; q < 8; ++q) {
        int r = i0 + w + 8 * q;
        av[q] = *(const float4*)(abase + (size_t)r * Nn);
        fi[q] = f1b[r];
    }
#pragma unroll
    for (int q = 0; q < 8; ++q) {
        int r = i0 + w + 8 * q;
        float u  = __expf(fi[q]);
        float up = __expf(ALPHA * fi[q]);
        bool n0 = av[q].x != 0.f, n1 = av[q].y != 0.f,
             n2 = av[q].z != 0.f, n3 = av[q].w != 0.f;
        float x0 = fi[q] + f2v.x, x1 = fi[q] + f2v.y,
              x2 = fi[q] + f2v.z, x3 = fi[q] + f2v.w;
        float e0 = x0 > 0.f ? u * vh0 : up * vp0;
        float e1 = x1 > 0.f ? u * vh1 : up * vp1;
        float e2 = x2 > 0.f ? u * vh2 : up * vp2;
        float e3 = x3 > 0.f ? u * vh3 : up * vp3;
        s0 += n0 ? e0 : ez0;
        s1 += n1 ? e1 : ez1;
        s2 += n2 ? e2 : ez2;
        s3 += n3 ? e3 : ez3;
        unsigned nib = (unsigned)n0 | ((unsigned)n1 << 1) |
                       ((unsigned)n2 << 2) | ((unsigned)n3 << 3);
        unsigned byt = nib | (((unsigned)__shfl_xor((int)nib, 1, 64)) << 4);
        unsigned h16 = byt | (((unsigned)__shfl_xor((int)byt, 2, 64)) << 8);
        unsigned w32 = h16 | (((unsigned)__shfl_xor((int)h16, 4, 64)) << 16);
        if ((lane & 7) == 0)
            bitsW[(size_t)(b * Nn + r) * 64 + cj8 + (lane >> 3)] = w32;
    }
    __shared__ float sred[8][256];
    sred[w][4 * lane + 0] = s0;
    sred[w][4 * lane + 1] = s1;
    sred[w][4 * lane + 2] = s2;
    sred[w][4 * lane + 3] = s3;
    __syncthreads();
    if (threadIdx.x < 256) {
        int c = threadIdx.x;
        float v = 0.f;
#pragma unroll
        for (int k = 0; k < 8; ++k) v += sred[k][c];
        atomicAdd(&Dsum[b * Nn + j0 + c], v);
    }
}

// ------- k2b: per-column table cf4 = {f2, vh/D, vp/D, ez/D}  +  rank-1 base C[b][o] = sum_j (ez_j/D_j) h[j][o] -------
// grid (Bn, Nn/64), block 256
__global__ __launch_bounds__(256) void k2b_cols(
        const float* __restrict__ h, const float* __restrict__ Dsum,
        const float* __restrict__ f2, const float* __restrict__ f1max_p,
        float4* __restrict__ cf4, float* __restrict__ C) {
    int b = blockIdx.x;
    int j0 = blockIdx.y * 64;
    int t = threadIdx.x;
    __shared__ float zl[64];
    if (t < 64) {
        int j = j0 + t;
        float f2j = f2[b * Nn + j];
        float Mf = fmaxf(lrelu(f1max_p[b] + f2j), 0.f);
        float invD = 1.f / Dsum[b * Nn + j];
        float vh = __expf(f2j - Mf) * invD;
        float vp = __expf(ALPHA * f2j - Mf) * invD;
        float ez = __expf(-Mf) * invD;
        cf4[b * Nn + j] = make_float4(f2j, vh, vp, ez);
        zl[t] = ez;
    }
    __syncthreads();
    int o = t & 63, g = t >> 6;      // 4 groups x 16 columns
    const float* hbp = h + ((size_t)(b * Nn + j0 + g * 16)) * Fn + o;
    float s = 0.f;
#pragma unroll
    for (int k = 0; k < 16; ++k) s = fmaf(zl[g * 16 + k], hbp[(size_t)k * Fn], s);
    atomicAdd(&C[b * Fn + o], s);
}

// ------- k3: one WAVE per output row, 4 rows/block, zero barriers -------
// Phase1: 64-lane bit decode -> LDS index list. Phase2: lanes parallel over
// neighbors computing weights -> LDS. Phase3: 4-at-a-time gather, 2 accumulators.
// grid (Bn*Nn/4), block 256
__global__ __launch_bounds__(256) void k3_row(
        const unsigned* __restrict__ bits, const float4* __restrict__ cf4,
        const float* __restrict__ f1, const float* __restrict__ h,
        const float* __restrict__ C, const float* __restrict__ inp,
        const float* __restrict__ bias, float* __restrict__ out) {
    int w = threadIdx.x >> 6, lane = threadIdx.x & 63;
    int gr = blockIdx.x * 4 + w;             // gr = b*Nn + i (rows contiguous)
    int b = gr >> 11, i = gr & (Nn - 1);
    __shared__ unsigned short lst[4][CAPR];
    __shared__ float wvs[4][CAPR];

    // phase 1: decode this row's 64 bit-words (one per lane)
    unsigned word = bits[(size_t)gr * 64 + lane];
    unsigned pc = (unsigned)__popc(word);
    unsigned pre = pc;
#pragma unroll
    for (int off = 1; off < 64; off <<= 1) {
        unsigned v = (unsigned)__shfl_up((int)pre, off, 64);
        if (lane >= off) pre += v;
    }
    unsigned base = pre - pc;
    int jbase = lane * 32;
    while (word) {
        int k = __ffs(word) - 1;
        word &= word - 1;
        if (base < CAPR) lst[w][base] = (unsigned short)(jbase + k);
        ++base;
    }
    unsigned cnt = (unsigned)__shfl((int)pre, 63, 64);
    if (cnt > CAPR) cnt = CAPR;

    float f1i = f1[gr];
    float ui = __expf(f1i), upi = __expf(ALPHA * f1i);
    const float4* cfb = cf4 + (size_t)b * Nn;

    // phase 2: per-neighbor weights, lanes parallel over neighbors
    for (unsigned t = lane; t < cnt; t += 64) {
        int j = lst[w][t];
        float4 cf = cfb[j];
        float x = f1i + cf.x;
        wvs[w][t] = (x > 0.f ? ui * cf.y : upi * cf.z) - cf.w;
    }

    // phase 3: gather h rows, lane = feature, 2 accumulators for fma ILP
    const float* hb = h + ((size_t)b * Nn) * Fn + lane;
    float acc0 = 0.f, acc1 = 0.f;
    unsigned t = 0;
    for (; t + 4 <= cnt; t += 4) {
        ushort4 j4 = *(const ushort4*)&lst[w][t];
        float4 w4 = *(const float4*)&wvs[w][t];
        float ha = hb[(size_t)j4.x * Fn];
        float hbv = hb[(size_t)j4.y * Fn];
        float hc = hb[(size_t)j4.z * Fn];
        float hd = hb[(size_t)j4.w * Fn];
        acc0 = fmaf(w4.x, ha, acc0);
        acc1 = fmaf(w4.y, hbv, acc1);
        acc0 = fmaf(w4.z, hc, acc0);
        acc1 = fmaf(w4.w, hd, acc1);
    }
    for (; t < cnt; ++t) {
        int j = lst[w][t];
        acc0 = fmaf(wvs[w][t], hb[(size_t)j * Fn], acc0);
    }
    float v = acc0 + acc1 + C[b * Fn + lane];
    size_t g = (size_t)gr * Fn + lane;
    out[g] = elu(v + inp[g] + bias[(size_t)i * Fn + lane]);
}

extern "C" void kernel_launch(void* const* d_in, const int* in_sizes, int n_in,
                              void* d_out, int out_size, void* d_ws, size_t ws_size,
                              hipStream_t stream) {
    const float* inp  = (const float*)d_in[0];
    const float* adj  = (const float*)d_in[1];
    const float* W    = (const float*)d_in[2];
    const float* a1   = (const float*)d_in[3];
    const float* a2   = (const float*)d_in[4];
    const float* bias = (const float*)d_in[5];
    float* out = (float*)d_out;

    // workspace layout (~8.5 MiB)
    char* ws = (char*)d_ws;
    unsigned* bitsW = (unsigned*)ws;                           // 8*2048*64*4 = 4,194,304
    float*  h     = (float*)(ws + 4194304);                    // 4,194,304
    float4* cf4   = (float4*)(ws + 8388608);                   //   262,144
    float*  f1    = (float*)(ws + 8650752);                    //    65,536
    float*  f2    = (float*)(ws + 8716288);                    //    65,536
    float*  f1max = (float*)(ws + 8781824);                    //        64 (pad)
    float*  Dsum  = (float*)(ws + 8781888);                    //    65,536 (zeroed)
    float*  C     = (float*)(ws + 8847424);                    //     2,048 (zeroed)

    hipMemsetAsync(ws + 8781888, 0, 65536 + 2048, stream);
    k1_h_f<<<Bn * Nn / 4, 256, 0, stream>>>(inp, W, a1, a2, h, f1, f2);
    k1b_max<<<Bn, 256, 0, stream>>>(f1, f1max);
    k2a_bits<<<dim3(Bn, 8, 32), 512, 0, stream>>>(adj, f1, f2, f1max, Dsum, bitsW);
    k2b_cols<<<dim3(Bn, Nn / 64), 256, 0, stream>>>(h, Dsum, f2, f1max, cf4, C);
    k3_row<<<Bn * Nn / 4, 256, 0, stream>>>(bitsW, cf4, f1, h, C, inp, bias, out);
}

// Round 4
// 256.938 us; speedup vs baseline: 1.5262x; 1.0217x over previous
//
#include <hip/hip_runtime.h>
#include <cstdint>
#include <cstddef>

#define Bn 8
#define Nn 2048
#define Fn 64
#define ALPHA 0.2f
#define CAPR 192   // per-row neighbor capacity; mean 102.4, sd 9.9 -> 9 sigma

__device__ __forceinline__ float elu(float x) { return x > 0.f ? x : __expf(x) - 1.f; }

// ---------------- k1: h = input@W, f1 = h@a1, f2 = h@a2 ----------------
__global__ __launch_bounds__(256) void k1_h_f(
        const float* __restrict__ inp, const float* __restrict__ W,
        const float* __restrict__ a1, const float* __restrict__ a2,
        float* __restrict__ h, float* __restrict__ f1, float* __restrict__ f2) {
    __shared__ float Wl[Fn * Fn];
    __shared__ float inr[4 * Fn];
    int t = threadIdx.x;
    for (int k = t; k < Fn * Fn; k += 256) Wl[k] = W[k];
    size_t row0 = (size_t)blockIdx.x * 4;
    inr[t] = inp[row0 * Fn + t];
    __syncthreads();
    int r = t >> 6, o = t & 63;
    const float* irow = &inr[r * Fn];
    float acc = 0.f;
#pragma unroll
    for (int f = 0; f < Fn; ++f) acc = fmaf(irow[f], Wl[f * Fn + o], acc);
    size_t row = row0 + r;
    h[row * Fn + o] = acc;
    float p = acc * a1[o];
    float q = acc * a2[o];
#pragma unroll
    for (int off = 32; off > 0; off >>= 1) {
        p += __shfl_down(p, off, 64);
        q += __shfl_down(q, off, 64);
    }
    if (o == 0) { f1[row] = p; f2[row] = q; }
}

// ------- k2a: stream adj once -> row-major bit words + column sums Dsum (rank-1, exp-free) -------
// M=0 formulation: softmax max-subtraction cancels exactly; exp args bounded ~e^34, safe in f32.
// grid (Bn, 8 colchunks of 256, 32 rowchunks of 64), block 512; 8 dwordx4 in flight upfront.
__global__ __launch_bounds__(512) void k2a_bits(
        const float* __restrict__ adj, const float* __restrict__ f1,
        const float* __restrict__ f2,
        float* __restrict__ Dsum, unsigned* __restrict__ bitsW) {
    int b = blockIdx.x;
    int j0 = blockIdx.y * 256;
    int cj8 = blockIdx.y * 8;
    int i0 = blockIdx.z * 64;
    int w = threadIdx.x >> 6, lane = threadIdx.x & 63;
    float4 f2v = *(const float4*)&f2[b * Nn + j0 + 4 * lane];
    float vh0 = __expf(f2v.x), vp0 = __expf(ALPHA * f2v.x);
    float vh1 = __expf(f2v.y), vp1 = __expf(ALPHA * f2v.y);
    float vh2 = __expf(f2v.z), vp2 = __expf(ALPHA * f2v.z);
    float vh3 = __expf(f2v.w), vp3 = __expf(ALPHA * f2v.w);
    float s0 = 0.f, s1 = 0.f, s2 = 0.f, s3 = 0.f;
    const float* abase = adj + ((size_t)b * Nn) * Nn + j0 + 4 * lane;
    const float* f1b = f1 + b * Nn;

    float4 av[8]; float fi[8];
#pragma unroll
    for (int q = 0; q < 8; ++q) {
        int r = i0 + w + 8 * q;
        av[q] = *(const float4*)(abase + (size_t)r * Nn);
        fi[q] = f1b[r];
    }
#pragma unroll
    for (int q = 0; q < 8; ++q) {
        int r = i0 + w + 8 * q;
        float u  = __expf(fi[q]);
        float up = __expf(ALPHA * fi[q]);
        bool n0 = av[q].x != 0.f, n1 = av[q].y != 0.f,
             n2 = av[q].z != 0.f, n3 = av[q].w != 0.f;
        float x0 = fi[q] + f2v.x, x1 = fi[q] + f2v.y,
              x2 = fi[q] + f2v.z, x3 = fi[q] + f2v.w;
        float e0 = x0 > 0.f ? u * vh0 : up * vp0;
        float e1 = x1 > 0.f ? u * vh1 : up * vp1;
        float e2 = x2 > 0.f ? u * vh2 : up * vp2;
        float e3 = x3 > 0.f ? u * vh3 : up * vp3;
        s0 += n0 ? e0 : 1.0f;
        s1 += n1 ? e1 : 1.0f;
        s2 += n2 ? e2 : 1.0f;
        s3 += n3 ? e3 : 1.0f;
        unsigned nib = (unsigned)n0 | ((unsigned)n1 << 1) |
                       ((unsigned)n2 << 2) | ((unsigned)n3 << 3);
        unsigned byt = nib | (((unsigned)__shfl_xor((int)nib, 1, 64)) << 4);
        unsigned h16 = byt | (((unsigned)__shfl_xor((int)byt, 2, 64)) << 8);
        unsigned w32 = h16 | (((unsigned)__shfl_xor((int)h16, 4, 64)) << 16);
        if ((lane & 7) == 0)
            bitsW[(size_t)(b * Nn + r) * 64 + cj8 + (lane >> 3)] = w32;
    }
    __shared__ float sred[8][256];
    sred[w][4 * lane + 0] = s0;
    sred[w][4 * lane + 1] = s1;
    sred[w][4 * lane + 2] = s2;
    sred[w][4 * lane + 3] = s3;
    __syncthreads();
    if (threadIdx.x < 256) {
        int c = threadIdx.x;
        float v = 0.f;
#pragma unroll
        for (int k = 0; k < 8; ++k) v += sred[k][c];
        atomicAdd(&Dsum[b * Nn + j0 + c], v);
    }
}

// ------- k2b: per-column table cf4 = {f2, e^f2/D, e^(a f2)/D, 1/D}  +  rank-1 base C[b][o] = sum_j h[j][o]/D_j -------
// grid (Bn, Nn/64), block 256
__global__ __launch_bounds__(256) void k2b_cols(
        const float* __restrict__ h, const float* __restrict__ Dsum,
        const float* __restrict__ f2,
        float4* __restrict__ cf4, float* __restrict__ C) {
    int b = blockIdx.x;
    int j0 = blockIdx.y * 64;
    int t = threadIdx.x;
    __shared__ float zl[64];
    if (t < 64) {
        int j = j0 + t;
        float f2j = f2[b * Nn + j];
        float invD = 1.f / Dsum[b * Nn + j];
        cf4[b * Nn + j] = make_float4(f2j, __expf(f2j) * invD,
                                      __expf(ALPHA * f2j) * invD, invD);
        zl[t] = invD;
    }
    __syncthreads();
    int o = t & 63, g = t >> 6;      // 4 groups x 16 columns
    const float* hbp = h + ((size_t)(b * Nn + j0 + g * 16)) * Fn + o;
    float s = 0.f;
#pragma unroll
    for (int k = 0; k < 16; ++k) s = fmaf(zl[g * 16 + k], hbp[(size_t)k * Fn], s);
    atomicAdd(&C[b * Fn + o], s);
}

// ------- k3: one WAVE per output row, 4 rows/block, zero barriers -------
// Phase1: 64-lane bit decode -> LDS byte-offset list. Phase2: lanes parallel over
// neighbors computing weights -> LDS. Phase3: unroll-8 gather, SGPR-base + 32-bit
// voffset loads (b is blockIdx-uniform), 4 accumulators.
// grid (Bn*Nn/4), block 256
__global__ __launch_bounds__(256) void k3_row(
        const unsigned* __restrict__ bits, const float4* __restrict__ cf4,
        const float* __restrict__ f1, const float* __restrict__ h,
        const float* __restrict__ C, const float* __restrict__ inp,
        const float* __restrict__ bias, float* __restrict__ out) {
    int w = threadIdx.x >> 6, lane = threadIdx.x & 63;
    int b = blockIdx.x >> 9;                      // uniform: 512 blocks per batch
    int i = ((blockIdx.x & 511) << 2) + w;
    int gr = (int)(blockIdx.x * 4) + w;           // = b*Nn + i
    __shared__ unsigned offs[4][CAPR];            // byte offsets j*256
    __shared__ float wvs[4][CAPR];

    // phase 1: decode this row's 64 bit-words (one per lane)
    unsigned word = bits[(size_t)gr * 64 + lane];
    unsigned pc = (unsigned)__popc(word);
    unsigned pre = pc;
#pragma unroll
    for (int off = 1; off < 64; off <<= 1) {
        unsigned v = (unsigned)__shfl_up((int)pre, off, 64);
        if (lane >= off) pre += v;
    }
    unsigned base = pre - pc;
    unsigned jb8 = ((unsigned)lane * 32u) << 8;
    while (word) {
        int k = __ffs(word) - 1;
        word &= word - 1;
        if (base < CAPR) offs[w][base] = jb8 + ((unsigned)k << 8);
        ++base;
    }
    unsigned cnt = (unsigned)__shfl((int)pre, 63, 64);
    if (cnt > CAPR) cnt = CAPR;

    float f1i = f1[gr];
    float ui = __expf(f1i), upi = __expf(ALPHA * f1i);
    const float4* cfb = cf4 + (size_t)b * Nn;

    // phase 2: per-neighbor weights, lanes parallel over neighbors
    for (unsigned t = lane; t < cnt; t += 64) {
        int j = (int)(offs[w][t] >> 8);
        float4 cf = cfb[j];
        float x = f1i + cf.x;
        wvs[w][t] = (x > 0.f ? ui * cf.y : upi * cf.z) - cf.w;
    }

    // phase 3: gather h rows; SGPR base + 32-bit voffset; 4 accs for fma ILP
    const char* hbase = (const char*)(h + (size_t)b * Nn * Fn);
    unsigned lane4 = (unsigned)lane << 2;
    float acc0 = 0.f, acc1 = 0.f, acc2 = 0.f, acc3 = 0.f;
    unsigned t = 0;
    for (; t + 8 <= cnt; t += 8) {
        uint4 oa = *(const uint4*)&offs[w][t];
        uint4 ob = *(const uint4*)&offs[w][t + 4];
        float4 wa = *(const float4*)&wvs[w][t];
        float4 wb = *(const float4*)&wvs[w][t + 4];
        float h0 = *(const float*)(hbase + (oa.x + lane4));
        float h1 = *(const float*)(hbase + (oa.y + lane4));
        float h2 = *(const float*)(hbase + (oa.z + lane4));
        float h3 = *(const float*)(hbase + (oa.w + lane4));
        float h4 = *(const float*)(hbase + (ob.x + lane4));
        float h5 = *(const float*)(hbase + (ob.y + lane4));
        float h6 = *(const float*)(hbase + (ob.z + lane4));
        float h7 = *(const float*)(hbase + (ob.w + lane4));
        acc0 = fmaf(wa.x, h0, acc0);
        acc1 = fmaf(wa.y, h1, acc1);
        acc2 = fmaf(wa.z, h2, acc2);
        acc3 = fmaf(wa.w, h3, acc3);
        acc0 = fmaf(wb.x, h4, acc0);
        acc1 = fmaf(wb.y, h5, acc1);
        acc2 = fmaf(wb.z, h6, acc2);
        acc3 = fmaf(wb.w, h7, acc3);
    }
    for (; t < cnt; ++t) {
        float hv = *(const float*)(hbase + (offs[w][t] + lane4));
        acc0 = fmaf(wvs[w][t], hv, acc0);
    }
    float v = (acc0 + acc1) + (acc2 + acc3) + C[b * Fn + lane];
    size_t g = (size_t)gr * Fn + lane;
    out[g] = elu(v + inp[g] + bias[(size_t)i * Fn + lane]);
}

extern "C" void kernel_launch(void* const* d_in, const int* in_sizes, int n_in,
                              void* d_out, int out_size, void* d_ws, size_t ws_size,
                              hipStream_t stream) {
    const float* inp  = (const float*)d_in[0];
    const float* adj  = (const float*)d_in[1];
    const float* W    = (const float*)d_in[2];
    const float* a1   = (const float*)d_in[3];
    const float* a2   = (const float*)d_in[4];
    const float* bias = (const float*)d_in[5];
    float* out = (float*)d_out;

    // workspace layout (~8.5 MiB)
    char* ws = (char*)d_ws;
    unsigned* bitsW = (unsigned*)ws;                           // 8*2048*64*4 = 4,194,304
    float*  h     = (float*)(ws + 4194304);                    // 4,194,304
    float4* cf4   = (float4*)(ws + 8388608);                   //   262,144
    float*  f1    = (float*)(ws + 8650752);                    //    65,536
    float*  f2    = (float*)(ws + 8716288);                    //    65,536
    float*  Dsum  = (float*)(ws + 8781824);                    //    65,536 (zeroed)
    float*  C     = (float*)(ws + 8847360);                    //     2,048 (zeroed)

    hipMemsetAsync(ws + 8781824, 0, 65536 + 2048, stream);
    k1_h_f<<<Bn * Nn / 4, 256, 0, stream>>>(inp, W, a1, a2, h, f1, f2);
    k2a_bits<<<dim3(Bn, 8, 32), 512, 0, stream>>>(adj, f1, f2, Dsum, bitsW);
    k2b_cols<<<dim3(Bn, Nn / 64), 256, 0, stream>>>(h, Dsum, f2, cf4, C);
    k3_row<<<Bn * Nn / 4, 256, 0, stream>>>(bitsW, cf4, f1, h, C, inp, bias, out);
}

// Round 6
// 237.357 us; speedup vs baseline: 1.6521x; 1.0825x over previous
//
#include <hip/hip_runtime.h>
#include <cstdint>
#include <cstddef>

#define Bn 8
#define Nn 2048
#define Fn 64
#define ALPHA 0.2f
#define CAPR 192   // per-row neighbor capacity; mean 102.4, sd 9.9 -> 9 sigma

typedef __attribute__((ext_vector_type(4))) float f4vec;

__device__ __forceinline__ float elu(float x) { return x > 0.f ? x : __expf(x) - 1.f; }
__device__ __forceinline__ float4 ntload4(const float* p) {
    f4vec v = __builtin_nontemporal_load((const f4vec*)p);
    return make_float4(v.x, v.y, v.z, v.w);
}

// ---------------- k1: h = input@W, f1 = h@a1, f2 = h@a2 (+ zero Dsum/C) ----------------
__global__ __launch_bounds__(256) void k1_h_f(
        const float* __restrict__ inp, const float* __restrict__ W,
        const float* __restrict__ a1, const float* __restrict__ a2,
        float* __restrict__ h, float* __restrict__ f1, float* __restrict__ f2,
        float* __restrict__ Dsum, float* __restrict__ C) {
    __shared__ float Wl[Fn * Fn];
    __shared__ float inr[4 * Fn];
    int t = threadIdx.x;
    // fold the old hipMemsetAsync into the first kernel (one fewer dispatch)
    if (blockIdx.x < 64) Dsum[blockIdx.x * 256 + t] = 0.f;
    else if (blockIdx.x == 64) { C[t] = 0.f; C[t + 256] = 0.f; }
    for (int k = t; k < Fn * Fn; k += 256) Wl[k] = W[k];
    size_t row0 = (size_t)blockIdx.x * 4;
    inr[t] = inp[row0 * Fn + t];
    __syncthreads();
    int r = t >> 6, o = t & 63;
    const float* irow = &inr[r * Fn];
    float acc = 0.f;
#pragma unroll
    for (int f = 0; f < Fn; ++f) acc = fmaf(irow[f], Wl[f * Fn + o], acc);
    size_t row = row0 + r;
    h[row * Fn + o] = acc;
    float p = acc * a1[o];
    float q = acc * a2[o];
#pragma unroll
    for (int off = 32; off > 0; off >>= 1) {
        p += __shfl_down(p, off, 64);
        q += __shfl_down(q, off, 64);
    }
    if (o == 0) { f1[row] = p; f2[row] = q; }
}

// ------- k2a: stream adj once -> row-major bit words + column sums Dsum (rank-1, exp-free) -------
// M=0 formulation: softmax max-subtraction cancels exactly; exp args bounded ~e^34, safe in f32.
// grid (Bn, 8 colchunks of 256, 32 rowchunks of 64), block 512; 8 dwordx4 in flight upfront.
__global__ __launch_bounds__(512) void k2a_bits(
        const float* __restrict__ adj, const float* __restrict__ f1,
        const float* __restrict__ f2,
        float* __restrict__ Dsum, unsigned* __restrict__ bitsW) {
    int b = blockIdx.x;
    int j0 = blockIdx.y * 256;
    int cj8 = blockIdx.y * 8;
    int i0 = blockIdx.z * 64;
    int w = threadIdx.x >> 6, lane = threadIdx.x & 63;
    float4 f2v = *(const float4*)&f2[b * Nn + j0 + 4 * lane];
    float vh0 = __expf(f2v.x), vp0 = __expf(ALPHA * f2v.x);
    float vh1 = __expf(f2v.y), vp1 = __expf(ALPHA * f2v.y);
    float vh2 = __expf(f2v.z), vp2 = __expf(ALPHA * f2v.z);
    float vh3 = __expf(f2v.w), vp3 = __expf(ALPHA * f2v.w);
    float s0 = 0.f, s1 = 0.f, s2 = 0.f, s3 = 0.f;
    const float* abase = adj + ((size_t)b * Nn) * Nn + j0 + 4 * lane;
    const float* f1b = f1 + b * Nn;

    float4 av[8]; float fi[8];
#pragma unroll
    for (int q = 0; q < 8; ++q) {
        int r = i0 + w + 8 * q;
        av[q] = ntload4(abase + (size_t)r * Nn);   // zero-reuse stream
        fi[q] = f1b[r];
    }
#pragma unroll
    for (int q = 0; q < 8; ++q) {
        int r = i0 + w + 8 * q;
        float u  = __expf(fi[q]);
        float up = __expf(ALPHA * fi[q]);
        bool n0 = av[q].x != 0.f, n1 = av[q].y != 0.f,
             n2 = av[q].z != 0.f, n3 = av[q].w != 0.f;
        float x0 = fi[q] + f2v.x, x1 = fi[q] + f2v.y,
              x2 = fi[q] + f2v.z, x3 = fi[q] + f2v.w;
        float e0 = x0 > 0.f ? u * vh0 : up * vp0;
        float e1 = x1 > 0.f ? u * vh1 : up * vp1;
        float e2 = x2 > 0.f ? u * vh2 : up * vp2;
        float e3 = x3 > 0.f ? u * vh3 : up * vp3;
        s0 += n0 ? e0 : 1.0f;
        s1 += n1 ? e1 : 1.0f;
        s2 += n2 ? e2 : 1.0f;
        s3 += n3 ? e3 : 1.0f;
        unsigned nib = (unsigned)n0 | ((unsigned)n1 << 1) |
                       ((unsigned)n2 << 2) | ((unsigned)n3 << 3);
        unsigned byt = nib | (((unsigned)__shfl_xor((int)nib, 1, 64)) << 4);
        unsigned h16 = byt | (((unsigned)__shfl_xor((int)byt, 2, 64)) << 8);
        unsigned w32 = h16 | (((unsigned)__shfl_xor((int)h16, 4, 64)) << 16);
        if ((lane & 7) == 0)
            bitsW[(size_t)(b * Nn + r) * 64 + cj8 + (lane >> 3)] = w32;
    }
    __shared__ float sred[8][256];
    sred[w][4 * lane + 0] = s0;
    sred[w][4 * lane + 1] = s1;
    sred[w][4 * lane + 2] = s2;
    sred[w][4 * lane + 3] = s3;
    __syncthreads();
    if (threadIdx.x < 256) {
        int c = threadIdx.x;
        float v = 0.f;
#pragma unroll
        for (int k = 0; k < 8; ++k) v += sred[k][c];
        atomicAdd(&Dsum[b * Nn + j0 + c], v);
    }
}

// ------- k2b: per-column table cf4 = {f2, e^f2/D, e^(a f2)/D, 1/D}  +  rank-1 base C[b][o] = sum_j h[j][o]/D_j -------
// grid (Bn, Nn/64), block 256
__global__ __launch_bounds__(256) void k2b_cols(
        const float* __restrict__ h, const float* __restrict__ Dsum,
        const float* __restrict__ f2,
        float4* __restrict__ cf4, float* __restrict__ C) {
    int b = blockIdx.x;
    int j0 = blockIdx.y * 64;
    int t = threadIdx.x;
    __shared__ float zl[64];
    if (t < 64) {
        int j = j0 + t;
        float f2j = f2[b * Nn + j];
        float invD = 1.f / Dsum[b * Nn + j];
        cf4[b * Nn + j] = make_float4(f2j, __expf(f2j) * invD,
                                      __expf(ALPHA * f2j) * invD, invD);
        zl[t] = invD;
    }
    __syncthreads();
    int o = t & 63, g = t >> 6;      // 4 groups x 16 columns
    const float* hbp = h + ((size_t)(b * Nn + j0 + g * 16)) * Fn + o;
    float s = 0.f;
#pragma unroll
    for (int k = 0; k < 16; ++k) s = fmaf(zl[g * 16 + k], hbp[(size_t)k * Fn], s);
    atomicAdd(&C[b * Fn + o], s);
}

// ------- k3: one WAVE per output row, 4 rows/block, zero barriers -------
// Phase1: 64-lane bit decode -> LDS byte-offset list. Phase2: fully-unrolled (<=3/lane)
// per-neighbor weights -> LDS. Phase3: unroll-16 gather (16 loads in flight), 4 accs.
// Epilogue operands (inp/bias/C) prefetched before phase 2.
// grid (Bn*Nn/4), block 256
__global__ __launch_bounds__(256) void k3_row(
        const unsigned* __restrict__ bits, const float4* __restrict__ cf4,
        const float* __restrict__ f1, const float* __restrict__ h,
        const float* __restrict__ C, const float* __restrict__ inp,
        const float* __restrict__ bias, float* __restrict__ out) {
    int w = threadIdx.x >> 6, lane = threadIdx.x & 63;
    int b = blockIdx.x >> 9;                      // uniform: 512 blocks per batch
    int i = ((blockIdx.x & 511) << 2) + w;
    int gr = (int)(blockIdx.x * 4) + w;           // = b*Nn + i
    __shared__ unsigned offs[4][CAPR];            // byte offsets j*256
    __shared__ float wvs[4][CAPR];

    // phase 1: decode this row's 64 bit-words (one per lane)
    unsigned word = bits[(size_t)gr * 64 + lane];
    unsigned pc = (unsigned)__popc(word);
    unsigned pre = pc;
#pragma unroll
    for (int off = 1; off < 64; off <<= 1) {
        unsigned v = (unsigned)__shfl_up((int)pre, off, 64);
        if (lane >= off) pre += v;
    }
    unsigned base = pre - pc;
    unsigned jb8 = ((unsigned)lane * 32u) << 8;
    while (word) {
        int k = __ffs(word) - 1;
        word &= word - 1;
        if (base < CAPR) offs[w][base] = jb8 + ((unsigned)k << 8);
        ++base;
    }
    unsigned cnt = (unsigned)__shfl((int)pre, 63, 64);
    if (cnt > CAPR) cnt = CAPR;

    float f1i = f1[gr];
    float ui = __expf(f1i), upi = __expf(ALPHA * f1i);
    const float4* cfp = cf4 + (size_t)b * Nn;

    // epilogue operands issued early: latency hides under phase 2/3
    size_t g = (size_t)gr * Fn + lane;
    float inv = inp[g];
    float bvv = bias[(size_t)i * Fn + lane];
    float Cv  = C[b * Fn + lane];

    // phase 2: per-neighbor weights, lanes parallel over neighbors, <=3 per lane (CAPR=192)
    {
        unsigned ta = lane, tb = lane + 64u, tc = lane + 128u;
        bool va = ta < cnt, vb = tb < cnt, vc = tc < cnt;
        float4 ca, cb, cc;
        if (va) ca = cfp[offs[w][ta] >> 8];
        if (vb) cb = cfp[offs[w][tb] >> 8];
        if (vc) cc = cfp[offs[w][tc] >> 8];
        if (va) { float x = f1i + ca.x; wvs[w][ta] = (x > 0.f ? ui * ca.y : upi * ca.z) - ca.w; }
        if (vb) { float x = f1i + cb.x; wvs[w][tb] = (x > 0.f ? ui * cb.y : upi * cb.z) - cb.w; }
        if (vc) { float x = f1i + cc.x; wvs[w][tc] = (x > 0.f ? ui * cc.y : upi * cc.z) - cc.w; }
    }

    // phase 3: gather h rows; SGPR base + 32-bit voffset; 16 loads in flight
    const char* hbase = (const char*)(h + (size_t)b * Nn * Fn);
    unsigned lane4 = (unsigned)lane << 2;
    float acc0 = 0.f, acc1 = 0.f, acc2 = 0.f, acc3 = 0.f;
    unsigned t = 0;
    for (; t + 16 <= cnt; t += 16) {
        uint4 oa = *(const uint4*)&offs[w][t];
        uint4 ob = *(const uint4*)&offs[w][t + 4];
        uint4 oc = *(const uint4*)&offs[w][t + 8];
        uint4 od = *(const uint4*)&offs[w][t + 12];
        float4 wa = *(const float4*)&wvs[w][t];
        float4 wb = *(const float4*)&wvs[w][t + 4];
        float4 wc = *(const float4*)&wvs[w][t + 8];
        float4 wd = *(const float4*)&wvs[w][t + 12];
        float h0 = *(const float*)(hbase + (oa.x + lane4));
        float h1 = *(const float*)(hbase + (oa.y + lane4));
        float h2 = *(const float*)(hbase + (oa.z + lane4));
        float h3 = *(const float*)(hbase + (oa.w + lane4));
        float h4 = *(const float*)(hbase + (ob.x + lane4));
        float h5 = *(const float*)(hbase + (ob.y + lane4));
        float h6 = *(const float*)(hbase + (ob.z + lane4));
        float h7 = *(const float*)(hbase + (ob.w + lane4));
        float h8 = *(const float*)(hbase + (oc.x + lane4));
        float h9 = *(const float*)(hbase + (oc.y + lane4));
        float hA = *(const float*)(hbase + (oc.z + lane4));
        float hB = *(const float*)(hbase + (oc.w + lane4));
        float hC = *(const float*)(hbase + (od.x + lane4));
        float hD = *(const float*)(hbase + (od.y + lane4));
        float hE = *(const float*)(hbase + (od.z + lane4));
        float hF = *(const float*)(hbase + (od.w + lane4));
        acc0 = fmaf(wa.x, h0, acc0);
        acc1 = fmaf(wa.y, h1, acc1);
        acc2 = fmaf(wa.z, h2, acc2);
        acc3 = fmaf(wa.w, h3, acc3);
        acc0 = fmaf(wb.x, h4, acc0);
        acc1 = fmaf(wb.y, h5, acc1);
        acc2 = fmaf(wb.z, h6, acc2);
        acc3 = fmaf(wb.w, h7, acc3);
        acc0 = fmaf(wc.x, h8, acc0);
        acc1 = fmaf(wc.y, h9, acc1);
        acc2 = fmaf(wc.z, hA, acc2);
        acc3 = fmaf(wc.w, hB, acc3);
        acc0 = fmaf(wd.x, hC, acc0);
        acc1 = fmaf(wd.y, hD, acc1);
        acc2 = fmaf(wd.z, hE, acc2);
        acc3 = fmaf(wd.w, hF, acc3);
    }
    for (; t + 4 <= cnt; t += 4) {
        uint4 oa = *(const uint4*)&offs[w][t];
        float4 wa = *(const float4*)&wvs[w][t];
        float h0 = *(const float*)(hbase + (oa.x + lane4));
        float h1 = *(const float*)(hbase + (oa.y + lane4));
        float h2 = *(const float*)(hbase + (oa.z + lane4));
        float h3 = *(const float*)(hbase + (oa.w + lane4));
        acc0 = fmaf(wa.x, h0, acc0);
        acc1 = fmaf(wa.y, h1, acc1);
        acc2 = fmaf(wa.z, h2, acc2);
        acc3 = fmaf(wa.w, h3, acc3);
    }
    for (; t < cnt; ++t) {
        float hv = *(const float*)(hbase + (offs[w][t] + lane4));
        acc0 = fmaf(wvs[w][t], hv, acc0);
    }
    float v = (acc0 + acc1) + (acc2 + acc3) + Cv;
    out[g] = elu(v + inv + bvv);
}

extern "C" void kernel_launch(void* const* d_in, const int* in_sizes, int n_in,
                              void* d_out, int out_size, void* d_ws, size_t ws_size,
                              hipStream_t stream) {
    const float* inp  = (const float*)d_in[0];
    const float* adj  = (const float*)d_in[1];
    const float* W    = (const float*)d_in[2];
    const float* a1   = (const float*)d_in[3];
    const float* a2   = (const float*)d_in[4];
    const float* bias = (const float*)d_in[5];
    float* out = (float*)d_out;

    // workspace layout (~8.5 MiB)
    char* ws = (char*)d_ws;
    unsigned* bitsW = (unsigned*)ws;                           // 8*2048*64*4 = 4,194,304
    float*  h     = (float*)(ws + 4194304);                    // 4,194,304
    float4* cf4   = (float4*)(ws + 8388608);                   //   262,144
    float*  f1    = (float*)(ws + 8650752);                    //    65,536
    float*  f2    = (float*)(ws + 8716288);                    //    65,536
    float*  Dsum  = (float*)(ws + 8781824);                    //    65,536 (zeroed in k1)
    float*  C     = (float*)(ws + 8847360);                    //     2,048 (zeroed in k1)

    k1_h_f<<<Bn * Nn / 4, 256, 0, stream>>>(inp, W, a1, a2, h, f1, f2, Dsum, C);
    k2a_bits<<<dim3(Bn, 8, 32), 512, 0, stream>>>(adj, f1, f2, Dsum, bitsW);
    k2b_cols<<<dim3(Bn, Nn / 64), 256, 0, stream>>>(h, Dsum, f2, cf4, C);
    k3_row<<<Bn * Nn / 4, 256, 0, stream>>>(bitsW, cf4, f1, h, C, inp, bias, out);
}